// Round 16
// baseline (170.185 us; speedup 1.0000x reference)
//
#include <hip/hip_runtime.h>
#include <hip/hip_bf16.h>

#define RELS 7
#define DIM 64

typedef __attribute__((ext_vector_type(8))) short short8;
typedef __attribute__((ext_vector_type(4))) short short4v;
typedef __attribute__((ext_vector_type(4))) float floatx4;

__device__ inline unsigned short f2b(float f) {
  union { float f; unsigned u; } v; v.f = f;
  unsigned u = v.u + 0x7fffu + ((v.u >> 16) & 1u);  // round-nearest-even
  return (unsigned short)(u >> 16);
}
__device__ inline float b2f(unsigned short b) {
  union { unsigned u; float f; } v; v.u = ((unsigned)b) << 16;
  return v.f;
}
__device__ inline short8 pack8(float4 a, float4 b) {
  short8 o;
  o[0] = (short)f2b(a.x); o[1] = (short)f2b(a.y);
  o[2] = (short)f2b(a.z); o[3] = (short)f2b(a.w);
  o[4] = (short)f2b(b.x); o[5] = (short)f2b(b.y);
  o[6] = (short)f2b(b.z); o[7] = (short)f2b(b.w);
  return o;
}

// Wcat^T as MFMA *A*-fragments (operand-swapped GEMM).
// frag = kk*32 + ctile; lane l holds A[c = ctile*16 + (l&15)][k = kk*32 + (l>>4)*8 + j]
// where A[c][k] = Wcat[k][c], c = r*64+o.
__global__ void __launch_bounds__(256) k_wcat(const float* __restrict__ W,
                                              const float* __restrict__ root,
                                              unsigned short* __restrict__ Bcat) {
  int g = blockIdx.x * 256 + threadIdx.x;  // 64 frags * 64 lanes = 4096
  if (g >= 4096) return;
  int frag = g >> 6, lane = g & 63;
  int kk = frag >> 5, ctile = frag & 31;
  int c = (ctile << 4) + (lane & 15);
  int r = c >> 6, o = c & 63;
  int kbase = (kk << 5) + ((lane >> 4) << 3);
  short8 tmp;
#pragma unroll
  for (int j = 0; j < 8; ++j) {
    int k = kbase + j;
    float v = (r < RELS) ? W[(r << 12) + (k << 6) + o] : root[(k << 6) + o];
    tmp[j] = (short)f2b(v);
  }
  *reinterpret_cast<short8*>(&Bcat[g * 8]) = tmp;
}

// xw[node*512 + c] = (x_node @ Wcat)[c], computed as D = Wcat^T x^T:
// D col (lane&15) = node, D rows (kg*4+q) = 4 consecutive c -> one 8B store.
__global__ void __launch_bounds__(256) k_xw(const float* __restrict__ x,
                                            const unsigned short* __restrict__ Bcat,
                                            unsigned short* __restrict__ xw, int N) {
  const int tid = threadIdx.x;
  const int lane = tid & 63;
  const int wv = tid >> 6;          // wave -> col block of 128
  const int row16 = lane & 15;
  const int kg = lane >> 4;
  const int i0 = blockIdx.x * 16;
  const int node = i0 + row16;
  const int nodec = (node < N) ? node : (N - 1);
  const bool ok = node < N;

  const float* xr = x + ((long)nodec << 6);
  float4 p0 = *reinterpret_cast<const float4*>(xr + (kg << 3));
  float4 p1 = *reinterpret_cast<const float4*>(xr + (kg << 3) + 4);
  float4 p2 = *reinterpret_cast<const float4*>(xr + 32 + (kg << 3));
  float4 p3 = *reinterpret_cast<const float4*>(xr + 32 + (kg << 3) + 4);
  short8 b0 = pack8(p0, p1);   // x fragment, k = 0..31
  short8 b1 = pack8(p2, p3);   // x fragment, k = 32..63
  const short8* Bv = reinterpret_cast<const short8*>(Bcat);
  unsigned short* orow = xw + ((long)node << 9) + (kg << 2);

#pragma unroll
  for (int T = 0; T < 8; ++T) {
    const int ctile = (wv << 3) + T;
    floatx4 acc = {0, 0, 0, 0};
    acc = __builtin_amdgcn_mfma_f32_16x16x32_bf16(Bv[(ctile << 6) + lane], b0, acc, 0, 0, 0);
    acc = __builtin_amdgcn_mfma_f32_16x16x32_bf16(Bv[((32 + ctile) << 6) + lane], b1, acc, 0, 0, 0);
    if (ok) {
      short4v s;
      s[0] = (short)f2b(acc[0]); s[1] = (short)f2b(acc[1]);
      s[2] = (short)f2b(acc[2]); s[3] = (short)f2b(acc[3]);
      *reinterpret_cast<short4v*>(orow + (ctile << 4)) = s;
    }
  }
}

// ONE atomic pass: rank[e] = atomicAdd(deg[seg]); afterwards deg = counts.
__global__ void __launch_bounds__(256) k_rank(const int* __restrict__ dst,
                                              const int* __restrict__ et,
                                              int* __restrict__ deg,
                                              unsigned short* __restrict__ rank, int E) {
  int e = blockIdx.x * 256 + threadIdx.x;
  if (e >= E) return;
  int seg = (dst[e] << 3) + et[e];
  int r = atomicAdd(&deg[seg], 1);
  rank[e] = (unsigned short)(r > 65535 ? 65535 : r);
}

// fused dpad+scan1: block scans padded degrees of 1024 nodes
__global__ void __launch_bounds__(256) k_scan1d(const int* __restrict__ deg,
                                                int* __restrict__ nst,
                                                int* __restrict__ bsum, int N) {
  __shared__ int sm[256];
  int t = threadIdx.x;
  int base = blockIdx.x * 1024 + t * 4;
  int d0 = 0, d1 = 0, d2 = 0, d3 = 0;
#pragma unroll
  for (int q = 0; q < 4; ++q) {
    int n = base + q;
    int s = 1;
    if (n < N) {
#pragma unroll
      for (int r = 0; r < RELS; ++r) s += deg[(n << 3) + r];
      s = (s + 7) & ~7;
      if (q == 0) d0 = s; else if (q == 1) d1 = s; else if (q == 2) d2 = s; else d3 = s;
    }
  }
  int s = d0 + d1 + d2 + d3;
  sm[t] = s;
  __syncthreads();
  for (int off = 1; off < 256; off <<= 1) {
    int a = (t >= off) ? sm[t - off] : 0;
    __syncthreads();
    sm[t] += a;
    __syncthreads();
  }
  int excl = sm[t] - s;
  if (base + 0 < N) nst[base + 0] = excl;
  excl += d0;
  if (base + 1 < N) nst[base + 1] = excl;
  excl += d1;
  if (base + 2 < N) nst[base + 2] = excl;
  excl += d2;
  if (base + 3 < N) nst[base + 3] = excl;
  if (t == 255) bsum[blockIdx.x] = sm[255];
}

// single-block exclusive scan over up to 1024 block sums (in place)
__global__ void __launch_bounds__(256) k_scan2(int* bsum, int nb) {
  __shared__ int sm[256];
  int t = threadIdx.x;
  int base = t * 4;
  int v0 = (base + 0 < nb) ? bsum[base + 0] : 0;
  int v1 = (base + 1 < nb) ? bsum[base + 1] : 0;
  int v2 = (base + 2 < nb) ? bsum[base + 2] : 0;
  int v3 = (base + 3 < nb) ? bsum[base + 3] : 0;
  int s = v0 + v1 + v2 + v3;
  sm[t] = s;
  __syncthreads();
  for (int off = 1; off < 256; off <<= 1) {
    int a = (t >= off) ? sm[t - off] : 0;
    __syncthreads();
    sm[t] += a;
    __syncthreads();
  }
  int excl = sm[t] - s;
  if (base + 0 < nb) bsum[base + 0] = excl;
  excl += v0;
  if (base + 1 < nb) bsum[base + 1] = excl;
  excl += v1;
  if (base + 2 < nb) bsum[base + 2] = excl;
  excl += v2;
  if (base + 3 < nb) bsum[base + 3] = excl;
}

// fused scan3b+prep: finalize nst, write per-seg cursors, self slot, pads
__global__ void __launch_bounds__(256) k_finprep(const int* __restrict__ deg,
                                                 int* __restrict__ nst,
                                                 const int* __restrict__ bsum,
                                                 int* __restrict__ cursor,
                                                 int* __restrict__ esrc, int N) {
  int i = blockIdx.x * 256 + threadIdx.x;
  if (i >= N) return;
  int v = nst[i] + bsum[i >> 10];
  nst[i] = v;
  int base = v;
#pragma unroll
  for (int r = 0; r < RELS; ++r) {
    int seg = (i << 3) + r;
    cursor[seg] = base;
    base += deg[seg];
  }
  esrc[base] = ((i << 3) | 7) | (1 << 20);  // self edge -> root row, c=1
  ++base;
  int dend = v + ((base - v + 7) & ~7);
  for (; base < dend; ++base) esrc[base] = 0;  // pad: row 0, c=0 -> w=0
  if (i == N - 1) nst[N] = dend;
}

// Atomic-free XCD-partitioned placement: pos = cursor[seg] + rank[e].
// word = row(20) | min(c,4095)<<20
__global__ void __launch_bounds__(256) k_place(const int* __restrict__ ei,
                                               const int* __restrict__ et,
                                               const int* __restrict__ deg,
                                               const int* __restrict__ cursor,
                                               const unsigned short* __restrict__ rank,
                                               int* __restrict__ esrc, int E, int N) {
  int p = blockIdx.x & 7;
  int e = (blockIdx.x >> 3) * 256 + threadIdx.x;
  if (e >= E) return;
  int Np = (N + 7) >> 3;
  int d = ei[E + e];
  if (d < p * Np || d >= (p + 1) * Np) return;
  int s = ei[e], r = et[e];
  int seg = (d << 3) + r;
  int pos = cursor[seg] + (int)rank[e];
  int c = deg[seg]; if (c > 4095) c = 4095;
  esrc[pos] = (s << 3) | r | (c << 20);
}

// one wave per node: out[nd] = sum_e w_e * xw[row_e] + bias
__global__ void __launch_bounds__(256) k_gather(const int* __restrict__ nst,
                                                const int* __restrict__ esrc,
                                                const unsigned short* __restrict__ xw,
                                                const float* __restrict__ bias,
                                                float* __restrict__ out, int N) {
  int nd = (int)(((long)blockIdx.x * 256 + threadIdx.x) >> 6);
  const int lane = threadIdx.x & 63;
  if (nd >= N) return;
  nd = __builtin_amdgcn_readfirstlane(nd);
  const int s    = __builtin_amdgcn_readfirstlane(nst[nd]);
  const int send = __builtin_amdgcn_readfirstlane(nst[nd + 1]);

  float a0 = 0, a1 = 0, a2 = 0, a3 = 0;
  const unsigned short* xwl = xw + lane;

  for (int e = s; e < send; e += 8) {
    int4 ia = *reinterpret_cast<const int4*>(esrc + e);
    int4 ib = *reinterpret_cast<const int4*>(esrc + e + 4);
    float g0 = b2f(xwl[((long)(ia.x & 0xFFFFF)) << 6]);
    float g1 = b2f(xwl[((long)(ia.y & 0xFFFFF)) << 6]);
    float g2 = b2f(xwl[((long)(ia.z & 0xFFFFF)) << 6]);
    float g3 = b2f(xwl[((long)(ia.w & 0xFFFFF)) << 6]);
    float g4 = b2f(xwl[((long)(ib.x & 0xFFFFF)) << 6]);
    float g5 = b2f(xwl[((long)(ib.y & 0xFFFFF)) << 6]);
    float g6 = b2f(xwl[((long)(ib.z & 0xFFFFF)) << 6]);
    float g7 = b2f(xwl[((long)(ib.w & 0xFFFFF)) << 6]);
    unsigned c0 = ((unsigned)ia.x) >> 20, c1 = ((unsigned)ia.y) >> 20;
    unsigned c2 = ((unsigned)ia.z) >> 20, c3 = ((unsigned)ia.w) >> 20;
    unsigned c4 = ((unsigned)ib.x) >> 20, c5 = ((unsigned)ib.y) >> 20;
    unsigned c6 = ((unsigned)ib.z) >> 20, c7 = ((unsigned)ib.w) >> 20;
    float w0 = c0 ? __builtin_amdgcn_rcpf((float)c0) : 0.0f;
    float w1 = c1 ? __builtin_amdgcn_rcpf((float)c1) : 0.0f;
    float w2 = c2 ? __builtin_amdgcn_rcpf((float)c2) : 0.0f;
    float w3 = c3 ? __builtin_amdgcn_rcpf((float)c3) : 0.0f;
    float w4 = c4 ? __builtin_amdgcn_rcpf((float)c4) : 0.0f;
    float w5 = c5 ? __builtin_amdgcn_rcpf((float)c5) : 0.0f;
    float w6 = c6 ? __builtin_amdgcn_rcpf((float)c6) : 0.0f;
    float w7 = c7 ? __builtin_amdgcn_rcpf((float)c7) : 0.0f;
    a0 += w0 * g0; a1 += w1 * g1; a2 += w2 * g2; a3 += w3 * g3;
    a0 += w4 * g4; a1 += w5 * g5; a2 += w6 * g6; a3 += w7 * g7;
  }

  float r = (a0 + a1) + (a2 + a3) + bias[lane];
  out[((long)nd << 6) + lane] = r;
}

extern "C" void kernel_launch(void* const* d_in, const int* in_sizes, int n_in,
                              void* d_out, int out_size, void* d_ws, size_t ws_size,
                              hipStream_t stream)
{
  const float* x    = (const float*)d_in[0];
  const float* W    = (const float*)d_in[1];
  const float* root = (const float*)d_in[2];
  const float* bias = (const float*)d_in[3];
  const int*   ei   = (const int*)d_in[4];
  const int*   et   = (const int*)d_in[5];
  float* out = (float*)d_out;

  const int N = in_sizes[0] / DIM;
  const int E = in_sizes[4] / 2;
  const int NS = N * 8;

  // workspace layout
  unsigned short* xw  = (unsigned short*)d_ws;            // [N*8][64] bf16 = 102.4 MB
  unsigned short* Bcat = xw + (size_t)NS * DIM;           // 64 KiB
  int*   esrc  = (int*)(Bcat + 4096 * 8);                 // [E + 8N]
  unsigned short* rank = (unsigned short*)(esrc + E + 8 * N);  // [E]
  int*   deg   = (int*)(rank + ((E + 1) & ~1));           // [NS]
  int*   nst   = deg + NS;                                // [N+1]
  int*   cursor = nst + N + 1;                            // [NS]
  int*   bsum  = cursor + NS;                             // [ceil(N/1024)]

  hipMemsetAsync(deg, 0, (size_t)NS * sizeof(int), stream);
  k_wcat<<<16, 256, 0, stream>>>(W, root, Bcat);
  k_rank<<<(E + 255) / 256, 256, 0, stream>>>(ei + E, et, deg, rank, E);
  k_xw<<<(N + 15) / 16, 256, 0, stream>>>(x, Bcat, xw, N);
  int nb = (N + 1023) / 1024;
  k_scan1d<<<nb, 256, 0, stream>>>(deg, nst, bsum, N);
  k_scan2<<<1, 256, 0, stream>>>(bsum, nb);
  k_finprep<<<(N + 255) / 256, 256, 0, stream>>>(deg, nst, bsum, cursor, esrc, N);
  int bpp = (E + 255) / 256;  // blocks per XCD partition
  k_place<<<bpp * 8, 256, 0, stream>>>(ei, et, deg, cursor, rank, esrc, E, N);
  k_gather<<<(N + 3) / 4, 256, 0, stream>>>(nst, esrc, xw, bias, out, N);
}

// Round 17
// 155.147 us; speedup vs baseline: 1.0969x; 1.0969x over previous
//
#include <hip/hip_runtime.h>
#include <hip/hip_bf16.h>

#define RELS 7
#define DIM 64

typedef __attribute__((ext_vector_type(8))) short short8;
typedef __attribute__((ext_vector_type(4))) float floatx4;

__device__ inline unsigned short f2b(float f) {
  union { float f; unsigned u; } v; v.f = f;
  unsigned u = v.u + 0x7fffu + ((v.u >> 16) & 1u);  // round-nearest-even
  return (unsigned short)(u >> 16);
}
__device__ inline float b2f(unsigned short b) {
  union { unsigned u; float f; } v; v.u = ((unsigned)b) << 16;
  return v.f;
}
__device__ inline short8 pack8(float4 a, float4 b) {
  short8 o;
  o[0] = (short)f2b(a.x); o[1] = (short)f2b(a.y);
  o[2] = (short)f2b(a.z); o[3] = (short)f2b(a.w);
  o[4] = (short)f2b(b.x); o[5] = (short)f2b(b.y);
  o[6] = (short)f2b(b.z); o[7] = (short)f2b(b.w);
  return o;
}

// Wcat^T as MFMA *A*-fragments (operand-swapped GEMM).
// frag = kk*32 + ctile; lane l holds A[c = ctile*16 + (l&15)][k = kk*32 + (l>>4)*8 + j]
// where A[c][k] = Wcat[k][c], c = r*64+o.
__global__ void __launch_bounds__(256) k_wcat(const float* __restrict__ W,
                                              const float* __restrict__ root,
                                              unsigned short* __restrict__ Bcat) {
  int g = blockIdx.x * 256 + threadIdx.x;  // 64 frags * 64 lanes = 4096
  if (g >= 4096) return;
  int frag = g >> 6, lane = g & 63;
  int kk = frag >> 5, ctile = frag & 31;
  int c = (ctile << 4) + (lane & 15);
  int r = c >> 6, o = c & 63;
  int kbase = (kk << 5) + ((lane >> 4) << 3);
  short8 tmp;
#pragma unroll
  for (int j = 0; j < 8; ++j) {
    int k = kbase + j;
    float v = (r < RELS) ? W[(r << 12) + (k << 6) + o] : root[(k << 6) + o];
    tmp[j] = (short)f2b(v);
  }
  *reinterpret_cast<short8*>(&Bcat[g * 8]) = tmp;
}

// xw[node*512 + c] = (x_node @ Wcat)[c]. Swapped MFMA (D row = c, col = node),
// results staged in LDS, then written out as full 1KB-per-wave coalesced rows.
#define LROW 520  // 512 + 8 pad shorts -> 2-way max bank aliasing on writes

__global__ void __launch_bounds__(256) k_xw(const float* __restrict__ x,
                                            const unsigned short* __restrict__ Bcat,
                                            unsigned short* __restrict__ xw, int N) {
  __shared__ unsigned short S[16 * LROW];  // 16.6 KiB
  const int tid = threadIdx.x;
  const int lane = tid & 63;
  const int wv = tid >> 6;          // wave -> col block of 128
  const int row16 = lane & 15;
  const int kg = lane >> 4;
  const int i0 = blockIdx.x * 16;
  const int node = i0 + row16;
  const int nodec = (node < N) ? node : (N - 1);

  const float* xr = x + ((long)nodec << 6);
  float4 p0 = *reinterpret_cast<const float4*>(xr + (kg << 3));
  float4 p1 = *reinterpret_cast<const float4*>(xr + (kg << 3) + 4);
  float4 p2 = *reinterpret_cast<const float4*>(xr + 32 + (kg << 3));
  float4 p3 = *reinterpret_cast<const float4*>(xr + 32 + (kg << 3) + 4);
  short8 b0 = pack8(p0, p1);   // x fragment, k = 0..31
  short8 b1 = pack8(p2, p3);   // x fragment, k = 32..63
  const short8* Bv = reinterpret_cast<const short8*>(Bcat);
  unsigned short* srow = S + row16 * LROW + (kg << 2);

#pragma unroll
  for (int T = 0; T < 8; ++T) {
    const int ctile = (wv << 3) + T;
    floatx4 acc = {0, 0, 0, 0};
    acc = __builtin_amdgcn_mfma_f32_16x16x32_bf16(Bv[(ctile << 6) + lane], b0, acc, 0, 0, 0);
    acc = __builtin_amdgcn_mfma_f32_16x16x32_bf16(Bv[((32 + ctile) << 6) + lane], b1, acc, 0, 0, 0);
    unsigned short* sp = srow + (ctile << 4);
    sp[0] = f2b(acc[0]); sp[1] = f2b(acc[1]);
    sp[2] = f2b(acc[2]); sp[3] = f2b(acc[3]);
  }
  __syncthreads();

  // write-out: wave wv stores rows 4*wv..4*wv+3; 64 lanes x 16B = 1KB/row
#pragma unroll
  for (int rr = 0; rr < 4; ++rr) {
    int row = (wv << 2) + rr;
    int g = i0 + row;
    if (g < N) {
      int4 v = *reinterpret_cast<const int4*>(S + row * LROW + (lane << 3));
      *reinterpret_cast<int4*>(xw + ((long)g << 9) + (lane << 3)) = v;
    }
  }
}

// ONE atomic pass: rank[e] = atomicAdd(deg[seg]); afterwards deg = counts.
__global__ void __launch_bounds__(256) k_rank(const int* __restrict__ dst,
                                              const int* __restrict__ et,
                                              int* __restrict__ deg,
                                              unsigned short* __restrict__ rank, int E) {
  int e = blockIdx.x * 256 + threadIdx.x;
  if (e >= E) return;
  int seg = (dst[e] << 3) + et[e];
  int r = atomicAdd(&deg[seg], 1);
  rank[e] = (unsigned short)(r > 65535 ? 65535 : r);
}

// fused dpad+scan1: block scans padded degrees of 1024 nodes
__global__ void __launch_bounds__(256) k_scan1d(const int* __restrict__ deg,
                                                int* __restrict__ nst,
                                                int* __restrict__ bsum, int N) {
  __shared__ int sm[256];
  int t = threadIdx.x;
  int base = blockIdx.x * 1024 + t * 4;
  int d0 = 0, d1 = 0, d2 = 0, d3 = 0;
#pragma unroll
  for (int q = 0; q < 4; ++q) {
    int n = base + q;
    int s = 1;
    if (n < N) {
#pragma unroll
      for (int r = 0; r < RELS; ++r) s += deg[(n << 3) + r];
      s = (s + 7) & ~7;
      if (q == 0) d0 = s; else if (q == 1) d1 = s; else if (q == 2) d2 = s; else d3 = s;
    }
  }
  int s = d0 + d1 + d2 + d3;
  sm[t] = s;
  __syncthreads();
  for (int off = 1; off < 256; off <<= 1) {
    int a = (t >= off) ? sm[t - off] : 0;
    __syncthreads();
    sm[t] += a;
    __syncthreads();
  }
  int excl = sm[t] - s;
  if (base + 0 < N) nst[base + 0] = excl;
  excl += d0;
  if (base + 1 < N) nst[base + 1] = excl;
  excl += d1;
  if (base + 2 < N) nst[base + 2] = excl;
  excl += d2;
  if (base + 3 < N) nst[base + 3] = excl;
  if (t == 255) bsum[blockIdx.x] = sm[255];
}

// single-block exclusive scan over up to 1024 block sums (in place)
__global__ void __launch_bounds__(256) k_scan2(int* bsum, int nb) {
  __shared__ int sm[256];
  int t = threadIdx.x;
  int base = t * 4;
  int v0 = (base + 0 < nb) ? bsum[base + 0] : 0;
  int v1 = (base + 1 < nb) ? bsum[base + 1] : 0;
  int v2 = (base + 2 < nb) ? bsum[base + 2] : 0;
  int v3 = (base + 3 < nb) ? bsum[base + 3] : 0;
  int s = v0 + v1 + v2 + v3;
  sm[t] = s;
  __syncthreads();
  for (int off = 1; off < 256; off <<= 1) {
    int a = (t >= off) ? sm[t - off] : 0;
    __syncthreads();
    sm[t] += a;
    __syncthreads();
  }
  int excl = sm[t] - s;
  if (base + 0 < nb) bsum[base + 0] = excl;
  excl += v0;
  if (base + 1 < nb) bsum[base + 1] = excl;
  excl += v1;
  if (base + 2 < nb) bsum[base + 2] = excl;
  excl += v2;
  if (base + 3 < nb) bsum[base + 3] = excl;
}

// fused scan3b+prep: finalize nst, write per-seg cursors, self slot, pads
__global__ void __launch_bounds__(256) k_finprep(const int* __restrict__ deg,
                                                 int* __restrict__ nst,
                                                 const int* __restrict__ bsum,
                                                 int* __restrict__ cursor,
                                                 int* __restrict__ esrc, int N) {
  int i = blockIdx.x * 256 + threadIdx.x;
  if (i >= N) return;
  int v = nst[i] + bsum[i >> 10];
  nst[i] = v;
  int base = v;
#pragma unroll
  for (int r = 0; r < RELS; ++r) {
    int seg = (i << 3) + r;
    cursor[seg] = base;
    base += deg[seg];
  }
  esrc[base] = ((i << 3) | 7) | (1 << 20);  // self edge -> root row, c=1
  ++base;
  int dend = v + ((base - v + 7) & ~7);
  for (; base < dend; ++base) esrc[base] = 0;  // pad: row 0, c=0 -> w=0
  if (i == N - 1) nst[N] = dend;
}

// Atomic-free XCD-partitioned placement: pos = cursor[seg] + rank[e].
// word = row(20) | min(c,4095)<<20
__global__ void __launch_bounds__(256) k_place(const int* __restrict__ ei,
                                               const int* __restrict__ et,
                                               const int* __restrict__ deg,
                                               const int* __restrict__ cursor,
                                               const unsigned short* __restrict__ rank,
                                               int* __restrict__ esrc, int E, int N) {
  int p = blockIdx.x & 7;
  int e = (blockIdx.x >> 3) * 256 + threadIdx.x;
  if (e >= E) return;
  int Np = (N + 7) >> 3;
  int d = ei[E + e];
  if (d < p * Np || d >= (p + 1) * Np) return;
  int s = ei[e], r = et[e];
  int seg = (d << 3) + r;
  int pos = cursor[seg] + (int)rank[e];
  int c = deg[seg]; if (c > 4095) c = 4095;
  esrc[pos] = (s << 3) | r | (c << 20);
}

// one wave per node: out[nd] = sum_e w_e * xw[row_e] + bias
__global__ void __launch_bounds__(256) k_gather(const int* __restrict__ nst,
                                                const int* __restrict__ esrc,
                                                const unsigned short* __restrict__ xw,
                                                const float* __restrict__ bias,
                                                float* __restrict__ out, int N) {
  int nd = (int)(((long)blockIdx.x * 256 + threadIdx.x) >> 6);
  const int lane = threadIdx.x & 63;
  if (nd >= N) return;
  nd = __builtin_amdgcn_readfirstlane(nd);
  const int s    = __builtin_amdgcn_readfirstlane(nst[nd]);
  const int send = __builtin_amdgcn_readfirstlane(nst[nd + 1]);

  float a0 = 0, a1 = 0, a2 = 0, a3 = 0;
  const unsigned short* xwl = xw + lane;

  for (int e = s; e < send; e += 8) {
    int4 ia = *reinterpret_cast<const int4*>(esrc + e);
    int4 ib = *reinterpret_cast<const int4*>(esrc + e + 4);
    float g0 = b2f(xwl[((long)(ia.x & 0xFFFFF)) << 6]);
    float g1 = b2f(xwl[((long)(ia.y & 0xFFFFF)) << 6]);
    float g2 = b2f(xwl[((long)(ia.z & 0xFFFFF)) << 6]);
    float g3 = b2f(xwl[((long)(ia.w & 0xFFFFF)) << 6]);
    float g4 = b2f(xwl[((long)(ib.x & 0xFFFFF)) << 6]);
    float g5 = b2f(xwl[((long)(ib.y & 0xFFFFF)) << 6]);
    float g6 = b2f(xwl[((long)(ib.z & 0xFFFFF)) << 6]);
    float g7 = b2f(xwl[((long)(ib.w & 0xFFFFF)) << 6]);
    unsigned c0 = ((unsigned)ia.x) >> 20, c1 = ((unsigned)ia.y) >> 20;
    unsigned c2 = ((unsigned)ia.z) >> 20, c3 = ((unsigned)ia.w) >> 20;
    unsigned c4 = ((unsigned)ib.x) >> 20, c5 = ((unsigned)ib.y) >> 20;
    unsigned c6 = ((unsigned)ib.z) >> 20, c7 = ((unsigned)ib.w) >> 20;
    float w0 = c0 ? __builtin_amdgcn_rcpf((float)c0) : 0.0f;
    float w1 = c1 ? __builtin_amdgcn_rcpf((float)c1) : 0.0f;
    float w2 = c2 ? __builtin_amdgcn_rcpf((float)c2) : 0.0f;
    float w3 = c3 ? __builtin_amdgcn_rcpf((float)c3) : 0.0f;
    float w4 = c4 ? __builtin_amdgcn_rcpf((float)c4) : 0.0f;
    float w5 = c5 ? __builtin_amdgcn_rcpf((float)c5) : 0.0f;
    float w6 = c6 ? __builtin_amdgcn_rcpf((float)c6) : 0.0f;
    float w7 = c7 ? __builtin_amdgcn_rcpf((float)c7) : 0.0f;
    a0 += w0 * g0; a1 += w1 * g1; a2 += w2 * g2; a3 += w3 * g3;
    a0 += w4 * g4; a1 += w5 * g5; a2 += w6 * g6; a3 += w7 * g7;
  }

  float r = (a0 + a1) + (a2 + a3) + bias[lane];
  out[((long)nd << 6) + lane] = r;
}

extern "C" void kernel_launch(void* const* d_in, const int* in_sizes, int n_in,
                              void* d_out, int out_size, void* d_ws, size_t ws_size,
                              hipStream_t stream)
{
  const float* x    = (const float*)d_in[0];
  const float* W    = (const float*)d_in[1];
  const float* root = (const float*)d_in[2];
  const float* bias = (const float*)d_in[3];
  const int*   ei   = (const int*)d_in[4];
  const int*   et   = (const int*)d_in[5];
  float* out = (float*)d_out;

  const int N = in_sizes[0] / DIM;
  const int E = in_sizes[4] / 2;
  const int NS = N * 8;

  // workspace layout
  unsigned short* xw  = (unsigned short*)d_ws;            // [N*8][64] bf16 = 102.4 MB
  unsigned short* Bcat = xw + (size_t)NS * DIM;           // 64 KiB
  int*   esrc  = (int*)(Bcat + 4096 * 8);                 // [E + 8N]
  unsigned short* rank = (unsigned short*)(esrc + E + 8 * N);  // [E]
  int*   deg   = (int*)(rank + ((E + 1) & ~1));           // [NS]
  int*   nst   = deg + NS;                                // [N+1]
  int*   cursor = nst + N + 1;                            // [NS]
  int*   bsum  = cursor + NS;                             // [ceil(N/1024)]

  hipMemsetAsync(deg, 0, (size_t)NS * sizeof(int), stream);
  k_wcat<<<16, 256, 0, stream>>>(W, root, Bcat);
  k_rank<<<(E + 255) / 256, 256, 0, stream>>>(ei + E, et, deg, rank, E);
  k_xw<<<(N + 15) / 16, 256, 0, stream>>>(x, Bcat, xw, N);
  int nb = (N + 1023) / 1024;
  k_scan1d<<<nb, 256, 0, stream>>>(deg, nst, bsum, N);
  k_scan2<<<1, 256, 0, stream>>>(bsum, nb);
  k_finprep<<<(N + 255) / 256, 256, 0, stream>>>(deg, nst, bsum, cursor, esrc, N);
  int bpp = (E + 255) / 256;  // blocks per XCD partition
  k_place<<<bpp * 8, 256, 0, stream>>>(ei, et, deg, cursor, rank, esrc, E, N);
  k_gather<<<(N + 3) / 4, 256, 0, stream>>>(nst, esrc, xw, bias, out, N);
}

// Round 18
// 154.370 us; speedup vs baseline: 1.1025x; 1.0050x over previous
//
#include <hip/hip_runtime.h>
#include <hip/hip_bf16.h>

#define RELS 7
#define DIM 64

typedef __attribute__((ext_vector_type(8))) short short8;
typedef __attribute__((ext_vector_type(4))) float floatx4;

__device__ inline unsigned short f2b(float f) {
  union { float f; unsigned u; } v; v.f = f;
  unsigned u = v.u + 0x7fffu + ((v.u >> 16) & 1u);  // round-nearest-even
  return (unsigned short)(u >> 16);
}
__device__ inline float b2f(unsigned short b) {
  union { unsigned u; float f; } v; v.u = ((unsigned)b) << 16;
  return v.f;
}
__device__ inline short8 pack8(float4 a, float4 b) {
  short8 o;
  o[0] = (short)f2b(a.x); o[1] = (short)f2b(a.y);
  o[2] = (short)f2b(a.z); o[3] = (short)f2b(a.w);
  o[4] = (short)f2b(b.x); o[5] = (short)f2b(b.y);
  o[6] = (short)f2b(b.z); o[7] = (short)f2b(b.w);
  return o;
}

// proper-grid zero fill (the rocclr fillBuffer kernel runs at 8% occupancy
// and cost 41 us for 3.2 MB — this does it in ~2 us)
__global__ void __launch_bounds__(256) k_zero(int4* __restrict__ p, int n4) {
  int i = blockIdx.x * 256 + threadIdx.x;
  if (i < n4) p[i] = make_int4(0, 0, 0, 0);
}

// Wcat^T as MFMA *A*-fragments (operand-swapped GEMM).
// frag = kk*32 + ctile; lane l holds A[c = ctile*16 + (l&15)][k = kk*32 + (l>>4)*8 + j]
// where A[c][k] = Wcat[k][c], c = r*64+o.
__global__ void __launch_bounds__(256) k_wcat(const float* __restrict__ W,
                                              const float* __restrict__ root,
                                              unsigned short* __restrict__ Bcat) {
  int g = blockIdx.x * 256 + threadIdx.x;  // 64 frags * 64 lanes = 4096
  if (g >= 4096) return;
  int frag = g >> 6, lane = g & 63;
  int kk = frag >> 5, ctile = frag & 31;
  int c = (ctile << 4) + (lane & 15);
  int r = c >> 6, o = c & 63;
  int kbase = (kk << 5) + ((lane >> 4) << 3);
  short8 tmp;
#pragma unroll
  for (int j = 0; j < 8; ++j) {
    int k = kbase + j;
    float v = (r < RELS) ? W[(r << 12) + (k << 6) + o] : root[(k << 6) + o];
    tmp[j] = (short)f2b(v);
  }
  *reinterpret_cast<short8*>(&Bcat[g * 8]) = tmp;
}

// xw[node*512 + c] = (x_node @ Wcat)[c]. Swapped MFMA (D row = c, col = node),
// results staged in LDS, then written out as full 1KB-per-wave coalesced rows.
#define LROW 520  // 512 + 8 pad shorts -> 2-way max bank aliasing on writes

__global__ void __launch_bounds__(256) k_xw(const float* __restrict__ x,
                                            const unsigned short* __restrict__ Bcat,
                                            unsigned short* __restrict__ xw, int N) {
  __shared__ unsigned short S[16 * LROW];  // 16.6 KiB
  const int tid = threadIdx.x;
  const int lane = tid & 63;
  const int wv = tid >> 6;          // wave -> col block of 128
  const int row16 = lane & 15;
  const int kg = lane >> 4;
  const int i0 = blockIdx.x * 16;
  const int node = i0 + row16;
  const int nodec = (node < N) ? node : (N - 1);

  const float* xr = x + ((long)nodec << 6);
  float4 p0 = *reinterpret_cast<const float4*>(xr + (kg << 3));
  float4 p1 = *reinterpret_cast<const float4*>(xr + (kg << 3) + 4);
  float4 p2 = *reinterpret_cast<const float4*>(xr + 32 + (kg << 3));
  float4 p3 = *reinterpret_cast<const float4*>(xr + 32 + (kg << 3) + 4);
  short8 b0 = pack8(p0, p1);   // x fragment, k = 0..31
  short8 b1 = pack8(p2, p3);   // x fragment, k = 32..63
  const short8* Bv = reinterpret_cast<const short8*>(Bcat);
  unsigned short* srow = S + row16 * LROW + (kg << 2);

#pragma unroll
  for (int T = 0; T < 8; ++T) {
    const int ctile = (wv << 3) + T;
    floatx4 acc = {0, 0, 0, 0};
    acc = __builtin_amdgcn_mfma_f32_16x16x32_bf16(Bv[(ctile << 6) + lane], b0, acc, 0, 0, 0);
    acc = __builtin_amdgcn_mfma_f32_16x16x32_bf16(Bv[((32 + ctile) << 6) + lane], b1, acc, 0, 0, 0);
    unsigned short* sp = srow + (ctile << 4);
    sp[0] = f2b(acc[0]); sp[1] = f2b(acc[1]);
    sp[2] = f2b(acc[2]); sp[3] = f2b(acc[3]);
  }
  __syncthreads();

  // write-out: wave wv stores rows 4*wv..4*wv+3; 64 lanes x 16B = 1KB/row
#pragma unroll
  for (int rr = 0; rr < 4; ++rr) {
    int row = (wv << 2) + rr;
    int g = i0 + row;
    if (g < N) {
      int4 v = *reinterpret_cast<const int4*>(S + row * LROW + (lane << 3));
      *reinterpret_cast<int4*>(xw + ((long)g << 9) + (lane << 3)) = v;
    }
  }
}

// ONE atomic pass: rank[e] = atomicAdd(deg[seg]); afterwards deg = counts.
__global__ void __launch_bounds__(256) k_rank(const int* __restrict__ dst,
                                              const int* __restrict__ et,
                                              int* __restrict__ deg,
                                              unsigned short* __restrict__ rank, int E) {
  int e = blockIdx.x * 256 + threadIdx.x;
  if (e >= E) return;
  int seg = (dst[e] << 3) + et[e];
  int r = atomicAdd(&deg[seg], 1);
  rank[e] = (unsigned short)(r > 65535 ? 65535 : r);
}

// fused dpad+scan1: block scans padded degrees of 1024 nodes
__global__ void __launch_bounds__(256) k_scan1d(const int* __restrict__ deg,
                                                int* __restrict__ nst,
                                                int* __restrict__ bsum, int N) {
  __shared__ int sm[256];
  int t = threadIdx.x;
  int base = blockIdx.x * 1024 + t * 4;
  int d0 = 0, d1 = 0, d2 = 0, d3 = 0;
#pragma unroll
  for (int q = 0; q < 4; ++q) {
    int n = base + q;
    int s = 1;
    if (n < N) {
#pragma unroll
      for (int r = 0; r < RELS; ++r) s += deg[(n << 3) + r];
      s = (s + 7) & ~7;
      if (q == 0) d0 = s; else if (q == 1) d1 = s; else if (q == 2) d2 = s; else d3 = s;
    }
  }
  int s = d0 + d1 + d2 + d3;
  sm[t] = s;
  __syncthreads();
  for (int off = 1; off < 256; off <<= 1) {
    int a = (t >= off) ? sm[t - off] : 0;
    __syncthreads();
    sm[t] += a;
    __syncthreads();
  }
  int excl = sm[t] - s;
  if (base + 0 < N) nst[base + 0] = excl;
  excl += d0;
  if (base + 1 < N) nst[base + 1] = excl;
  excl += d1;
  if (base + 2 < N) nst[base + 2] = excl;
  excl += d2;
  if (base + 3 < N) nst[base + 3] = excl;
  if (t == 255) bsum[blockIdx.x] = sm[255];
}

// single-block exclusive scan over up to 1024 block sums (in place)
__global__ void __launch_bounds__(256) k_scan2(int* bsum, int nb) {
  __shared__ int sm[256];
  int t = threadIdx.x;
  int base = t * 4;
  int v0 = (base + 0 < nb) ? bsum[base + 0] : 0;
  int v1 = (base + 1 < nb) ? bsum[base + 1] : 0;
  int v2 = (base + 2 < nb) ? bsum[base + 2] : 0;
  int v3 = (base + 3 < nb) ? bsum[base + 3] : 0;
  int s = v0 + v1 + v2 + v3;
  sm[t] = s;
  __syncthreads();
  for (int off = 1; off < 256; off <<= 1) {
    int a = (t >= off) ? sm[t - off] : 0;
    __syncthreads();
    sm[t] += a;
    __syncthreads();
  }
  int excl = sm[t] - s;
  if (base + 0 < nb) bsum[base + 0] = excl;
  excl += v0;
  if (base + 1 < nb) bsum[base + 1] = excl;
  excl += v1;
  if (base + 2 < nb) bsum[base + 2] = excl;
  excl += v2;
  if (base + 3 < nb) bsum[base + 3] = excl;
}

// fused scan3b+prep: finalize nst, write per-seg cursors, self slot, pads
__global__ void __launch_bounds__(256) k_finprep(const int* __restrict__ deg,
                                                 int* __restrict__ nst,
                                                 const int* __restrict__ bsum,
                                                 int* __restrict__ cursor,
                                                 int* __restrict__ esrc, int N) {
  int i = blockIdx.x * 256 + threadIdx.x;
  if (i >= N) return;
  int v = nst[i] + bsum[i >> 10];
  nst[i] = v;
  int base = v;
#pragma unroll
  for (int r = 0; r < RELS; ++r) {
    int seg = (i << 3) + r;
    cursor[seg] = base;
    base += deg[seg];
  }
  esrc[base] = ((i << 3) | 7) | (1 << 20);  // self edge -> root row, c=1
  ++base;
  int dend = v + ((base - v + 7) & ~7);
  for (; base < dend; ++base) esrc[base] = 0;  // pad: row 0, c=0 -> w=0
  if (i == N - 1) nst[N] = dend;
}

// Atomic-free XCD-partitioned placement: pos = cursor[seg] + rank[e].
// word = row(20) | min(c,4095)<<20
__global__ void __launch_bounds__(256) k_place(const int* __restrict__ ei,
                                               const int* __restrict__ et,
                                               const int* __restrict__ deg,
                                               const int* __restrict__ cursor,
                                               const unsigned short* __restrict__ rank,
                                               int* __restrict__ esrc, int E, int N) {
  int p = blockIdx.x & 7;
  int e = (blockIdx.x >> 3) * 256 + threadIdx.x;
  if (e >= E) return;
  int Np = (N + 7) >> 3;
  int d = ei[E + e];
  if (d < p * Np || d >= (p + 1) * Np) return;
  int s = ei[e], r = et[e];
  int seg = (d << 3) + r;
  int pos = cursor[seg] + (int)rank[e];
  int c = deg[seg]; if (c > 4095) c = 4095;
  esrc[pos] = (s << 3) | r | (c << 20);
}

// one wave per node: out[nd] = sum_e w_e * xw[row_e] + bias
__global__ void __launch_bounds__(256) k_gather(const int* __restrict__ nst,
                                                const int* __restrict__ esrc,
                                                const unsigned short* __restrict__ xw,
                                                const float* __restrict__ bias,
                                                float* __restrict__ out, int N) {
  int nd = (int)(((long)blockIdx.x * 256 + threadIdx.x) >> 6);
  const int lane = threadIdx.x & 63;
  if (nd >= N) return;
  nd = __builtin_amdgcn_readfirstlane(nd);
  const int s    = __builtin_amdgcn_readfirstlane(nst[nd]);
  const int send = __builtin_amdgcn_readfirstlane(nst[nd + 1]);

  float a0 = 0, a1 = 0, a2 = 0, a3 = 0;
  const unsigned short* xwl = xw + lane;

  for (int e = s; e < send; e += 8) {
    int4 ia = *reinterpret_cast<const int4*>(esrc + e);
    int4 ib = *reinterpret_cast<const int4*>(esrc + e + 4);
    float g0 = b2f(xwl[((long)(ia.x & 0xFFFFF)) << 6]);
    float g1 = b2f(xwl[((long)(ia.y & 0xFFFFF)) << 6]);
    float g2 = b2f(xwl[((long)(ia.z & 0xFFFFF)) << 6]);
    float g3 = b2f(xwl[((long)(ia.w & 0xFFFFF)) << 6]);
    float g4 = b2f(xwl[((long)(ib.x & 0xFFFFF)) << 6]);
    float g5 = b2f(xwl[((long)(ib.y & 0xFFFFF)) << 6]);
    float g6 = b2f(xwl[((long)(ib.z & 0xFFFFF)) << 6]);
    float g7 = b2f(xwl[((long)(ib.w & 0xFFFFF)) << 6]);
    unsigned c0 = ((unsigned)ia.x) >> 20, c1 = ((unsigned)ia.y) >> 20;
    unsigned c2 = ((unsigned)ia.z) >> 20, c3 = ((unsigned)ia.w) >> 20;
    unsigned c4 = ((unsigned)ib.x) >> 20, c5 = ((unsigned)ib.y) >> 20;
    unsigned c6 = ((unsigned)ib.z) >> 20, c7 = ((unsigned)ib.w) >> 20;
    float w0 = c0 ? __builtin_amdgcn_rcpf((float)c0) : 0.0f;
    float w1 = c1 ? __builtin_amdgcn_rcpf((float)c1) : 0.0f;
    float w2 = c2 ? __builtin_amdgcn_rcpf((float)c2) : 0.0f;
    float w3 = c3 ? __builtin_amdgcn_rcpf((float)c3) : 0.0f;
    float w4 = c4 ? __builtin_amdgcn_rcpf((float)c4) : 0.0f;
    float w5 = c5 ? __builtin_amdgcn_rcpf((float)c5) : 0.0f;
    float w6 = c6 ? __builtin_amdgcn_rcpf((float)c6) : 0.0f;
    float w7 = c7 ? __builtin_amdgcn_rcpf((float)c7) : 0.0f;
    a0 += w0 * g0; a1 += w1 * g1; a2 += w2 * g2; a3 += w3 * g3;
    a0 += w4 * g4; a1 += w5 * g5; a2 += w6 * g6; a3 += w7 * g7;
  }

  float r = (a0 + a1) + (a2 + a3) + bias[lane];
  out[((long)nd << 6) + lane] = r;
}

extern "C" void kernel_launch(void* const* d_in, const int* in_sizes, int n_in,
                              void* d_out, int out_size, void* d_ws, size_t ws_size,
                              hipStream_t stream)
{
  const float* x    = (const float*)d_in[0];
  const float* W    = (const float*)d_in[1];
  const float* root = (const float*)d_in[2];
  const float* bias = (const float*)d_in[3];
  const int*   ei   = (const int*)d_in[4];
  const int*   et   = (const int*)d_in[5];
  float* out = (float*)d_out;

  const int N = in_sizes[0] / DIM;
  const int E = in_sizes[4] / 2;
  const int NS = N * 8;

  // workspace layout
  unsigned short* xw  = (unsigned short*)d_ws;            // [N*8][64] bf16 = 102.4 MB
  unsigned short* Bcat = xw + (size_t)NS * DIM;           // 64 KiB
  int*   esrc  = (int*)(Bcat + 4096 * 8);                 // [E + 8N]
  unsigned short* rank = (unsigned short*)(esrc + E + 8 * N);  // [E]
  int*   deg   = (int*)(rank + ((E + 1) & ~1));           // [NS]
  int*   nst   = deg + NS;                                // [N+1]
  int*   cursor = nst + N + 1;                            // [NS]
  int*   bsum  = cursor + NS;                             // [ceil(N/1024)]

  int n4 = NS / 4;  // NS divisible by 4 (N*8)
  k_zero<<<(n4 + 255) / 256, 256, 0, stream>>>((int4*)deg, n4);
  k_wcat<<<16, 256, 0, stream>>>(W, root, Bcat);
  k_rank<<<(E + 255) / 256, 256, 0, stream>>>(ei + E, et, deg, rank, E);
  k_xw<<<(N + 15) / 16, 256, 0, stream>>>(x, Bcat, xw, N);
  int nb = (N + 1023) / 1024;
  k_scan1d<<<nb, 256, 0, stream>>>(deg, nst, bsum, N);
  k_scan2<<<1, 256, 0, stream>>>(bsum, nb);
  k_finprep<<<(N + 255) / 256, 256, 0, stream>>>(deg, nst, bsum, cursor, esrc, N);
  int bpp = (E + 255) / 256;  // blocks per XCD partition
  k_place<<<bpp * 8, 256, 0, stream>>>(ei, et, deg, cursor, rank, esrc, E, N);
  k_gather<<<(N + 3) / 4, 256, 0, stream>>>(nst, esrc, xw, bias, out, N);
}

// Round 19
// 148.439 us; speedup vs baseline: 1.1465x; 1.0400x over previous
//
#include <hip/hip_runtime.h>
#include <hip/hip_bf16.h>

#define RELS 7
#define DIM 64

typedef __attribute__((ext_vector_type(8))) short short8;
typedef __attribute__((ext_vector_type(4))) float floatx4;

__device__ inline unsigned short f2b(float f) {
  union { float f; unsigned u; } v; v.f = f;
  unsigned u = v.u + 0x7fffu + ((v.u >> 16) & 1u);  // round-nearest-even
  return (unsigned short)(u >> 16);
}
__device__ inline float b2f(unsigned short b) {
  union { unsigned u; float f; } v; v.u = ((unsigned)b) << 16;
  return v.f;
}
__device__ inline short8 pack8(float4 a, float4 b) {
  short8 o;
  o[0] = (short)f2b(a.x); o[1] = (short)f2b(a.y);
  o[2] = (short)f2b(a.z); o[3] = (short)f2b(a.w);
  o[4] = (short)f2b(b.x); o[5] = (short)f2b(b.y);
  o[6] = (short)f2b(b.z); o[7] = (short)f2b(b.w);
  return o;
}

// proper-grid zero fill
__global__ void __launch_bounds__(256) k_zero(int4* __restrict__ p, int n4) {
  int i = blockIdx.x * 256 + threadIdx.x;
  if (i < n4) p[i] = make_int4(0, 0, 0, 0);
}

// Wcat^T as MFMA *A*-fragments (operand-swapped GEMM).
__global__ void __launch_bounds__(256) k_wcat(const float* __restrict__ W,
                                              const float* __restrict__ root,
                                              unsigned short* __restrict__ Bcat) {
  int g = blockIdx.x * 256 + threadIdx.x;  // 64 frags * 64 lanes = 4096
  if (g >= 4096) return;
  int frag = g >> 6, lane = g & 63;
  int kk = frag >> 5, ctile = frag & 31;
  int c = (ctile << 4) + (lane & 15);
  int r = c >> 6, o = c & 63;
  int kbase = (kk << 5) + ((lane >> 4) << 3);
  short8 tmp;
#pragma unroll
  for (int j = 0; j < 8; ++j) {
    int k = kbase + j;
    float v = (r < RELS) ? W[(r << 12) + (k << 6) + o] : root[(k << 6) + o];
    tmp[j] = (short)f2b(v);
  }
  *reinterpret_cast<short8*>(&Bcat[g * 8]) = tmp;
}

// Heterogeneous fused dispatch:
//   blocks [0, RKB)   : rank role — rank[e] = atomicAdd(deg[seg],1)  (atomic-
//                       unit bound, all other pipes idle)
//   blocks [RKB, ...) : xw role — LDS-staged swapped-MFMA GEMM with full-line
//                       1KB/wave coalesced stores (no L2 merge residency
//                       needed -> R14's eviction-amplification can't recur)
#define LROW 520  // 512 + 8 pad shorts

__global__ void __launch_bounds__(256) k_xwrank(
    const float* __restrict__ x, const unsigned short* __restrict__ Bcat,
    unsigned short* __restrict__ xw,
    const int* __restrict__ dst, const int* __restrict__ et,
    int* __restrict__ deg, unsigned short* __restrict__ rank,
    int N, int E, int RKB)
{
  __shared__ unsigned short S[16 * LROW];  // 16.6 KiB (also allocated for rank blocks)

  if ((int)blockIdx.x < RKB) {
    // ---- rank role: 4 edges per thread ----
    int base = blockIdx.x * 1024 + threadIdx.x;
#pragma unroll
    for (int k = 0; k < 4; ++k) {
      int e = base + k * 256;
      if (e < E) {
        int seg = (dst[e] << 3) + et[e];
        int r = atomicAdd(&deg[seg], 1);
        rank[e] = (unsigned short)(r > 65535 ? 65535 : r);
      }
    }
    return;
  }

  // ---- xw role ----
  const int bid = blockIdx.x - RKB;
  const int tid = threadIdx.x;
  const int lane = tid & 63;
  const int wv = tid >> 6;
  const int row16 = lane & 15;
  const int kg = lane >> 4;
  const int i0 = bid * 16;
  const int node = i0 + row16;
  const int nodec = (node < N) ? node : (N - 1);

  const float* xr = x + ((long)nodec << 6);
  float4 p0 = *reinterpret_cast<const float4*>(xr + (kg << 3));
  float4 p1 = *reinterpret_cast<const float4*>(xr + (kg << 3) + 4);
  float4 p2 = *reinterpret_cast<const float4*>(xr + 32 + (kg << 3));
  float4 p3 = *reinterpret_cast<const float4*>(xr + 32 + (kg << 3) + 4);
  short8 b0 = pack8(p0, p1);   // x fragment, k = 0..31
  short8 b1 = pack8(p2, p3);   // x fragment, k = 32..63
  const short8* Bv = reinterpret_cast<const short8*>(Bcat);
  unsigned short* srow = S + row16 * LROW + (kg << 2);

#pragma unroll
  for (int T = 0; T < 8; ++T) {
    const int ctile = (wv << 3) + T;
    floatx4 acc = {0, 0, 0, 0};
    acc = __builtin_amdgcn_mfma_f32_16x16x32_bf16(Bv[(ctile << 6) + lane], b0, acc, 0, 0, 0);
    acc = __builtin_amdgcn_mfma_f32_16x16x32_bf16(Bv[((32 + ctile) << 6) + lane], b1, acc, 0, 0, 0);
    unsigned short* sp = srow + (ctile << 4);
    sp[0] = f2b(acc[0]); sp[1] = f2b(acc[1]);
    sp[2] = f2b(acc[2]); sp[3] = f2b(acc[3]);
  }
  __syncthreads();

#pragma unroll
  for (int rr = 0; rr < 4; ++rr) {
    int row = (wv << 2) + rr;
    int g = i0 + row;
    if (g < N) {
      int4 v = *reinterpret_cast<const int4*>(S + row * LROW + (lane << 3));
      *reinterpret_cast<int4*>(xw + ((long)g << 9) + (lane << 3)) = v;
    }
  }
}

// fused dpad+scan1: block scans padded degrees of 1024 nodes
__global__ void __launch_bounds__(256) k_scan1d(const int* __restrict__ deg,
                                                int* __restrict__ nst,
                                                int* __restrict__ bsum, int N) {
  __shared__ int sm[256];
  int t = threadIdx.x;
  int base = blockIdx.x * 1024 + t * 4;
  int d0 = 0, d1 = 0, d2 = 0, d3 = 0;
#pragma unroll
  for (int q = 0; q < 4; ++q) {
    int n = base + q;
    int s = 1;
    if (n < N) {
#pragma unroll
      for (int r = 0; r < RELS; ++r) s += deg[(n << 3) + r];
      s = (s + 7) & ~7;
      if (q == 0) d0 = s; else if (q == 1) d1 = s; else if (q == 2) d2 = s; else d3 = s;
    }
  }
  int s = d0 + d1 + d2 + d3;
  sm[t] = s;
  __syncthreads();
  for (int off = 1; off < 256; off <<= 1) {
    int a = (t >= off) ? sm[t - off] : 0;
    __syncthreads();
    sm[t] += a;
    __syncthreads();
  }
  int excl = sm[t] - s;
  if (base + 0 < N) nst[base + 0] = excl;
  excl += d0;
  if (base + 1 < N) nst[base + 1] = excl;
  excl += d1;
  if (base + 2 < N) nst[base + 2] = excl;
  excl += d2;
  if (base + 3 < N) nst[base + 3] = excl;
  if (t == 255) bsum[blockIdx.x] = sm[255];
}

// single-block exclusive scan over up to 1024 block sums (in place)
__global__ void __launch_bounds__(256) k_scan2(int* bsum, int nb) {
  __shared__ int sm[256];
  int t = threadIdx.x;
  int base = t * 4;
  int v0 = (base + 0 < nb) ? bsum[base + 0] : 0;
  int v1 = (base + 1 < nb) ? bsum[base + 1] : 0;
  int v2 = (base + 2 < nb) ? bsum[base + 2] : 0;
  int v3 = (base + 3 < nb) ? bsum[base + 3] : 0;
  int s = v0 + v1 + v2 + v3;
  sm[t] = s;
  __syncthreads();
  for (int off = 1; off < 256; off <<= 1) {
    int a = (t >= off) ? sm[t - off] : 0;
    __syncthreads();
    sm[t] += a;
    __syncthreads();
  }
  int excl = sm[t] - s;
  if (base + 0 < nb) bsum[base + 0] = excl;
  excl += v0;
  if (base + 1 < nb) bsum[base + 1] = excl;
  excl += v1;
  if (base + 2 < nb) bsum[base + 2] = excl;
  excl += v2;
  if (base + 3 < nb) bsum[base + 3] = excl;
}

// fused scan3b+prep: finalize nst, write per-seg cursors, self slot, pads
__global__ void __launch_bounds__(256) k_finprep(const int* __restrict__ deg,
                                                 int* __restrict__ nst,
                                                 const int* __restrict__ bsum,
                                                 int* __restrict__ cursor,
                                                 int* __restrict__ esrc, int N) {
  int i = blockIdx.x * 256 + threadIdx.x;
  if (i >= N) return;
  int v = nst[i] + bsum[i >> 10];
  nst[i] = v;
  int base = v;
#pragma unroll
  for (int r = 0; r < RELS; ++r) {
    int seg = (i << 3) + r;
    cursor[seg] = base;
    base += deg[seg];
  }
  esrc[base] = ((i << 3) | 7) | (1 << 20);  // self edge -> root row, c=1
  ++base;
  int dend = v + ((base - v + 7) & ~7);
  for (; base < dend; ++base) esrc[base] = 0;  // pad: row 0, c=0 -> w=0
  if (i == N - 1) nst[N] = dend;
}

// Atomic-free XCD-partitioned placement: pos = cursor[seg] + rank[e].
__global__ void __launch_bounds__(256) k_place(const int* __restrict__ ei,
                                               const int* __restrict__ et,
                                               const int* __restrict__ deg,
                                               const int* __restrict__ cursor,
                                               const unsigned short* __restrict__ rank,
                                               int* __restrict__ esrc, int E, int N) {
  int p = blockIdx.x & 7;
  int e = (blockIdx.x >> 3) * 256 + threadIdx.x;
  if (e >= E) return;
  int Np = (N + 7) >> 3;
  int d = ei[E + e];
  if (d < p * Np || d >= (p + 1) * Np) return;
  int s = ei[e], r = et[e];
  int seg = (d << 3) + r;
  int pos = cursor[seg] + (int)rank[e];
  int c = deg[seg]; if (c > 4095) c = 4095;
  esrc[pos] = (s << 3) | r | (c << 20);
}

// one wave per node: out[nd] = sum_e w_e * xw[row_e] + bias
__global__ void __launch_bounds__(256) k_gather(const int* __restrict__ nst,
                                                const int* __restrict__ esrc,
                                                const unsigned short* __restrict__ xw,
                                                const float* __restrict__ bias,
                                                float* __restrict__ out, int N) {
  int nd = (int)(((long)blockIdx.x * 256 + threadIdx.x) >> 6);
  const int lane = threadIdx.x & 63;
  if (nd >= N) return;
  nd = __builtin_amdgcn_readfirstlane(nd);
  const int s    = __builtin_amdgcn_readfirstlane(nst[nd]);
  const int send = __builtin_amdgcn_readfirstlane(nst[nd + 1]);

  float a0 = 0, a1 = 0, a2 = 0, a3 = 0;
  const unsigned short* xwl = xw + lane;

  for (int e = s; e < send; e += 8) {
    int4 ia = *reinterpret_cast<const int4*>(esrc + e);
    int4 ib = *reinterpret_cast<const int4*>(esrc + e + 4);
    float g0 = b2f(xwl[((long)(ia.x & 0xFFFFF)) << 6]);
    float g1 = b2f(xwl[((long)(ia.y & 0xFFFFF)) << 6]);
    float g2 = b2f(xwl[((long)(ia.z & 0xFFFFF)) << 6]);
    float g3 = b2f(xwl[((long)(ia.w & 0xFFFFF)) << 6]);
    float g4 = b2f(xwl[((long)(ib.x & 0xFFFFF)) << 6]);
    float g5 = b2f(xwl[((long)(ib.y & 0xFFFFF)) << 6]);
    float g6 = b2f(xwl[((long)(ib.z & 0xFFFFF)) << 6]);
    float g7 = b2f(xwl[((long)(ib.w & 0xFFFFF)) << 6]);
    unsigned c0 = ((unsigned)ia.x) >> 20, c1 = ((unsigned)ia.y) >> 20;
    unsigned c2 = ((unsigned)ia.z) >> 20, c3 = ((unsigned)ia.w) >> 20;
    unsigned c4 = ((unsigned)ib.x) >> 20, c5 = ((unsigned)ib.y) >> 20;
    unsigned c6 = ((unsigned)ib.z) >> 20, c7 = ((unsigned)ib.w) >> 20;
    float w0 = c0 ? __builtin_amdgcn_rcpf((float)c0) : 0.0f;
    float w1 = c1 ? __builtin_amdgcn_rcpf((float)c1) : 0.0f;
    float w2 = c2 ? __builtin_amdgcn_rcpf((float)c2) : 0.0f;
    float w3 = c3 ? __builtin_amdgcn_rcpf((float)c3) : 0.0f;
    float w4 = c4 ? __builtin_amdgcn_rcpf((float)c4) : 0.0f;
    float w5 = c5 ? __builtin_amdgcn_rcpf((float)c5) : 0.0f;
    float w6 = c6 ? __builtin_amdgcn_rcpf((float)c6) : 0.0f;
    float w7 = c7 ? __builtin_amdgcn_rcpf((float)c7) : 0.0f;
    a0 += w0 * g0; a1 += w1 * g1; a2 += w2 * g2; a3 += w3 * g3;
    a0 += w4 * g4; a1 += w5 * g5; a2 += w6 * g6; a3 += w7 * g7;
  }

  float r = (a0 + a1) + (a2 + a3) + bias[lane];
  out[((long)nd << 6) + lane] = r;
}

extern "C" void kernel_launch(void* const* d_in, const int* in_sizes, int n_in,
                              void* d_out, int out_size, void* d_ws, size_t ws_size,
                              hipStream_t stream)
{
  const float* x    = (const float*)d_in[0];
  const float* W    = (const float*)d_in[1];
  const float* root = (const float*)d_in[2];
  const float* bias = (const float*)d_in[3];
  const int*   ei   = (const int*)d_in[4];
  const int*   et   = (const int*)d_in[5];
  float* out = (float*)d_out;

  const int N = in_sizes[0] / DIM;
  const int E = in_sizes[4] / 2;
  const int NS = N * 8;

  // workspace layout
  unsigned short* xw  = (unsigned short*)d_ws;            // [N*8][64] bf16 = 102.4 MB
  unsigned short* Bcat = xw + (size_t)NS * DIM;           // 64 KiB
  int*   esrc  = (int*)(Bcat + 4096 * 8);                 // [E + 8N]
  unsigned short* rank = (unsigned short*)(esrc + E + 8 * N);  // [E]
  int*   deg   = (int*)(rank + ((E + 1) & ~1));           // [NS]
  int*   nst   = deg + NS;                                // [N+1]
  int*   cursor = nst + N + 1;                            // [NS]
  int*   bsum  = cursor + NS;                             // [ceil(N/1024)]

  int n4 = NS / 4;
  k_zero<<<(n4 + 255) / 256, 256, 0, stream>>>((int4*)deg, n4);
  k_wcat<<<16, 256, 0, stream>>>(W, root, Bcat);
  int RKB = (E + 1023) / 1024;
  int NBX = (N + 15) / 16;
  k_xwrank<<<RKB + NBX, 256, 0, stream>>>(x, Bcat, xw, ei + E, et, deg, rank,
                                          N, E, RKB);
  int nb = (N + 1023) / 1024;
  k_scan1d<<<nb, 256, 0, stream>>>(deg, nst, bsum, N);
  k_scan2<<<1, 256, 0, stream>>>(bsum, nb);
  k_finprep<<<(N + 255) / 256, 256, 0, stream>>>(deg, nst, bsum, cursor, esrc, N);
  int bpp = (E + 255) / 256;  // blocks per XCD partition
  k_place<<<bpp * 8, 256, 0, stream>>>(ei, et, deg, cursor, rank, esrc, E, N);
  k_gather<<<(N + 3) / 4, 256, 0, stream>>>(nst, esrc, xw, bias, out, N);
}